// Round 5
// baseline (66.070 us; speedup 1.0000x reference)
//
#include <hip/hip_runtime.h>
#include <cstdint>
#include <cstddef>

// Problem constants (from reference)
constexpr int B = 8, C = 96, N = 3136, K = 18;
constexpr float C1c = 1e-6f, C2c = 1e-6f;

__device__ inline float readlane_f(float v, int l) {
  return __builtin_bit_cast(float,
                            __builtin_amdgcn_readlane(__builtin_bit_cast(int, v), l));
}

// ---------------------------------------------------------------------------
// Kernel A (fused): transpose x,xp [B,C,N]->[B,N,C] AND per-column channel
// sums of x (cstat = {Σx, Σx²}). XCD-pinned: blockIdx&7 == batch.
// ---------------------------------------------------------------------------
__global__ __launch_bounds__(256) void fusedT_kernel(
    const float* __restrict__ x, const float* __restrict__ xp,
    float* __restrict__ xT, float* __restrict__ xpT,
    float2* __restrict__ cstat) {
  __shared__ float t0[C][33];
  __shared__ float t1[C][33];
  __shared__ float red1[8][33];
  __shared__ float red2[8][33];
  const int bid = blockIdx.x;
  const int b = bid & 7;              // XCD pin
  const int n0 = (bid >> 3) * 32;
  const int tx = threadIdx.x & 31;
  const int ty = threadIdx.x >> 5;

  const float* xb = x + (size_t)b * C * N;
  const float* xpb = xp + (size_t)b * C * N;
  float s = 0.f, s2 = 0.f;
#pragma unroll
  for (int st = 0; st < 12; ++st) {
    const int c = st * 8 + ty;
    const float v = xb[(size_t)c * N + n0 + tx];
    const float u = xpb[(size_t)c * N + n0 + tx];
    t0[c][tx] = v;
    t1[c][tx] = u;
    s += v;
    s2 += v * v;
  }
  red1[ty][tx] = s;
  red2[ty][tx] = s2;
  __syncthreads();

  float* xTb = xT + (size_t)b * N * C;
  float* xpTb = xpT + (size_t)b * N * C;
  const int tid = threadIdx.x;
#pragma unroll
  for (int r = 0; r < 12; ++r) {
    const int f = r * 256 + tid;      // f = nl*96 + c, coalesced
    const int nl = f / 96;
    const int c = f - nl * 96;
    xTb[(size_t)(n0 + nl) * C + c] = t0[c][nl];
    xpTb[(size_t)(n0 + nl) * C + c] = t1[c][nl];
  }
  if (ty == 0) {
    float S = 0.f, S2 = 0.f;
#pragma unroll
    for (int yy = 0; yy < 8; ++yy) {
      S += red1[yy][tx];
      S2 += red2[yy][tx];
    }
    cstat[(size_t)b * N + n0 + tx] = make_float2(S, S2);
  }
}

// ---------------------------------------------------------------------------
// Kernel B: main fused kernel. One wave per (b,n); XCD-pinned (blockIdx&7=b).
// Order chosen for memory-level parallelism:
//   (0) load edge indices, broadcast to SGPRs
//   (1) ISSUE all 36 xp column loads (48-lane float2 layout, A[18]/Q[18])
//   (2) phase 1: group-parallel dots (lane=8g+w, group g owns k={g,g+8,g+16},
//       3-level butterfly in-group) + group-parallel sff -> 18 SGPRs
//       -- xp loads from (1) are in flight under all of phase 1 --
//   (3) consume: t=Σ(a+q) and fma(|a-q|, sff_k) per channel
//   (4) coalesced float2 write to outT[B,N,C]
// __launch_bounds__(256,4): 128-VGPR budget so the compiler keeps A/Q hoisted.
// ---------------------------------------------------------------------------
__global__ __launch_bounds__(256, 4) void ssim_main_kernel(
    const float* __restrict__ xT, const float* __restrict__ xpT,
    const float2* __restrict__ cstat, const int* __restrict__ eidx,
    float* __restrict__ outT) {
  const int wave = threadIdx.x >> 6;
  const int lane = threadIdx.x & 63;
  const int b = blockIdx.x & 7;       // XCD pin: batch == blockIdx % 8
  const int tile = blockIdx.x >> 3;
  const int n = tile * 4 + wave;

  // lanes 0..17 -> j_k (edge_index[0]), lanes 18..35 -> i_k (edge_index[1])
  int myidx = 0;
  if (lane < 36) {
    const int s = (lane >= 18) ? 1 : 0;
    const int k = lane - 18 * s;
    myidx = eidx[((size_t)(s * B + b) * N + n) * K + k];
  }

  // Wave-uniform column indices in SGPRs
  int jjs[K], jis[K];
#pragma unroll
  for (int k = 0; k < K; ++k) {
    jjs[k] = __builtin_amdgcn_readlane(myidx, k);
    jis[k] = __builtin_amdgcn_readlane(myidx, 18 + k);
  }

  const float* xb = xT + (size_t)b * N * C;
  const float2* xpb2 = (const float2*)(xpT + (size_t)b * N * C);
  const float2* cs = cstat + (size_t)b * N;

  // ---- (1) issue ALL xp gathers now; latency hides under phase 1 ---------
  const int l48 = (lane < 48) ? lane : 47;  // lanes 48-63 duplicate lane 47
  float2 A[K], Q[K];
#pragma unroll
  for (int k = 0; k < K; ++k) {
    A[k] = xpb2[(size_t)jis[k] * 48 + l48];
    Q[k] = xpb2[(size_t)jjs[k] * 48 + l48];
  }

  // ---- (2) group-parallel dots + sff -------------------------------------
  const int g = lane >> 3;
  const int w = lane & 7;
  float sffr[3];
#pragma unroll
  for (int r = 0; r < 3; ++r) {
    int k = r * 8 + g;
    if (k > K - 1) k = K - 1;         // round 2, groups 2..7: redundant k=17
    const int cj = __shfl(myidx, k, 64);
    const int ci = __shfl(myidx, 18 + k, 64);
    const float* pi = xb + (size_t)ci * C + w * 12;
    const float* pj = xb + (size_t)cj * C + w * 12;
    const float4 a0 = *(const float4*)pi;
    const float4 a1 = *(const float4*)(pi + 4);
    const float4 a2 = *(const float4*)(pi + 8);
    const float4 q0 = *(const float4*)pj;
    const float4 q1 = *(const float4*)(pj + 4);
    const float4 q2 = *(const float4*)(pj + 8);
    float p = a0.x * q0.x + a0.y * q0.y + a0.z * q0.z + a0.w * q0.w;
    p += a1.x * q1.x + a1.y * q1.y + a1.z * q1.z + a1.w * q1.w;
    p += a2.x * q2.x + a2.y * q2.y + a2.z * q2.z + a2.w * q2.w;
    p += __shfl_xor(p, 1, 64);        // butterfly within the 8-lane group
    p += __shfl_xor(p, 2, 64);
    p += __shfl_xor(p, 4, 64);

    const float2 si = cs[ci];
    const float2 sj = cs[cj];
    const float mi = si.x * (1.0f / C), mj = sj.x * (1.0f / C);
    const float vi = si.y * (1.0f / C) - mi * mi;
    const float vj = sj.y * (1.0f / C) - mj * mj;
    const float cov = p * (1.0f / C) - mi * mj;
    const float S1 =
        (2.f * mi * mj + C1c) * __builtin_amdgcn_rcpf(mi * mi + mj * mj + C1c);
    const float S2 = (2.f * cov + C2c) * __builtin_amdgcn_rcpf(vi + vj + C2c);
    sffr[r] = 1.f - S1 * S2;
  }

  // sff_k -> wave-uniform SGPRs (group g's first lane is 8*(k&7))
  float sk[K];
#pragma unroll
  for (int k = 0; k < K; ++k) sk[k] = readlane_f(sffr[k >> 3], (k & 7) * 8);

  // ---- (3) consume xp registers ------------------------------------------
  float t_x = 0.f, t_y = 0.f, ax = 0.f, ay = 0.f;
#pragma unroll
  for (int k = 0; k < K; ++k) {
    t_x += A[k].x + Q[k].x;
    t_y += A[k].y + Q[k].y;
    ax = fmaf(fabsf(A[k].x - Q[k].x), sk[k], ax);
    ay = fmaf(fabsf(A[k].y - Q[k].y), sk[k], ay);
  }

  // ---- (4) coalesced write -----------------------------------------------
  if (lane < 48) {
    float2* ob = (float2*)(outT + ((size_t)b * N + n) * C);
    ob[lane] = make_float2(t_x + ax, t_y + ay);
  }
}

// ---------------------------------------------------------------------------
// Kernel C: transpose back outT [B,N,C] -> out [B,C,N], XCD-pinned.
// ---------------------------------------------------------------------------
__global__ __launch_bounds__(256) void transpose_back_kernel(
    const float* __restrict__ outT, float* __restrict__ out) {
  __shared__ float t[32][33];
  const int bid = blockIdx.x;
  const int b = bid & 7;              // XCD pin
  const int rest = bid >> 3;          // 0..293
  const int cb = rest / 98;           // 0..2
  const int nb = rest - cb * 98;      // 0..97
  const int n0 = nb * 32, c0 = cb * 32;
  const int tx = threadIdx.x & 31, ty = threadIdx.x >> 5;
  const float* ib = outT + (size_t)b * N * C;
#pragma unroll
  for (int i = 0; i < 4; ++i) {
    const int nn = n0 + ty + i * 8;
    t[ty + i * 8][tx] = ib[(size_t)nn * C + c0 + tx];
  }
  __syncthreads();
  float* ob = out + (size_t)b * C * N;
#pragma unroll
  for (int i = 0; i < 4; ++i) {
    const int c = c0 + ty + i * 8;
    ob[(size_t)c * N + n0 + tx] = t[tx][ty + i * 8];
  }
}

// ---------------------------------------------------------------------------
// Fallback (only used if ws_size is too small): slow but correct.
// ---------------------------------------------------------------------------
__global__ void fallback_kernel(const float* __restrict__ x,
                                const float* __restrict__ xp,
                                const int* __restrict__ e,
                                float* __restrict__ out) {
  const int gn = blockIdx.x * 64 + threadIdx.x;
  if (gn >= B * N) return;
  const int b = gn / N;
  const int n = gn - b * N;
  const float* xb = x + (size_t)b * C * N;
  const float* xpb = xp + (size_t)b * C * N;
  int ii[K], jj[K];
  float sff[K];
#pragma unroll
  for (int k = 0; k < K; ++k) {
    jj[k] = e[((size_t)(0 * B + b) * N + n) * K + k];
    ii[k] = e[((size_t)(1 * B + b) * N + n) * K + k];
    float si = 0, sj = 0, sii = 0, sjj = 0, sij = 0;
    for (int c = 0; c < C; ++c) {
      const float a = xb[(size_t)c * N + ii[k]];
      const float q = xb[(size_t)c * N + jj[k]];
      si += a; sj += q; sii += a * a; sjj += q * q; sij += a * q;
    }
    const float mi = si * (1.f / C), mj = sj * (1.f / C);
    const float vi = sii * (1.f / C) - mi * mi;
    const float vj = sjj * (1.f / C) - mj * mj;
    const float cov = sij * (1.f / C) - mi * mj;
    const float S1 = (2.f * mi * mj + C1c) / (mi * mi + mj * mj + C1c);
    const float S2 = (2.f * cov + C2c) / (vi + vj + C2c);
    sff[k] = 1.f - S1 * S2;
  }
  for (int c = 0; c < C; ++c) {
    float acc = 0.f;
#pragma unroll
    for (int k = 0; k < K; ++k) {
      const float a = xpb[(size_t)c * N + ii[k]];
      const float q = xpb[(size_t)c * N + jj[k]];
      acc += a + q + fabsf(a - q) * sff[k];
    }
    out[((size_t)b * C + c) * N + n] = acc;
  }
}

// ---------------------------------------------------------------------------
extern "C" void kernel_launch(void* const* d_in, const int* in_sizes, int n_in,
                              void* d_out, int out_size, void* d_ws, size_t ws_size,
                              hipStream_t stream) {
  const float* x = (const float*)d_in[0];
  const float* xp = (const float*)d_in[1];
  const int* e = (const int*)d_in[2];
  float* out = (float*)d_out;

  const size_t nBNC = (size_t)B * N * C;
  const size_t nBN = (size_t)B * N;
  const size_t need = 3 * nBNC * sizeof(float) + nBN * sizeof(float2);

  if (ws_size >= need) {
    float* ws = (float*)d_ws;
    float* xT = ws;
    float* xpT = xT + nBNC;
    float* outT = xpT + nBNC;
    float2* cstat = (float2*)(outT + nBNC);

    fusedT_kernel<<<8 * (N / 32), 256, 0, stream>>>(x, xp, xT, xpT, cstat);
    ssim_main_kernel<<<(B * N) / 4, 256, 0, stream>>>(xT, xpT, cstat, e, outT);
    transpose_back_kernel<<<8 * 3 * (N / 32), 256, 0, stream>>>(outT, out);
  } else {
    fallback_kernel<<<(B * N + 63) / 64, 64, 0, stream>>>(x, xp, e, out);
  }
}